// Round 7
// baseline (1924.096 us; speedup 1.0000x reference)
//
#include <hip/hip_runtime.h>

#define B_SZ 32
#define T_STEPS 64
#define N_IN 64
#define N_HID 512
#define N_OUT 16
#define NOISE_START_T 16

#define WGS 512           // 8 waves/WG
#define WPB 32            // workgroups per batch
#define JPW 16            // j columns per WG
#define EPT 16            // rows per thread
#define NWG (B_SZ * WPB)  // 1024

// d_out float offsets (hidden_list, output_list, hidden, new_j)
#define HL_OFF  0
#define OL_OFF  (B_SZ * T_STEPS * N_HID)
#define HID_OFF (OL_OFF + B_SZ * T_STEPS * N_OUT)
#define NJ_OFF  (HID_OFF + B_SZ * N_HID)

#define CNT_BYTES 4096
// wsf float offsets
#define HEX_OFF 0
#define AEX_OFF (2 * B_SZ * N_HID)
#define XWG_OFF (4 * B_SZ * N_HID)   // [1024 wg][64 t][16 jl]

typedef float v2f __attribute__((ext_vector_type(2)));

__device__ __forceinline__ void tf2x32(unsigned k0, unsigned k1, unsigned x0, unsigned x1,
                                       unsigned& o0, unsigned& o1) {
  unsigned ks2 = k0 ^ k1 ^ 0x1BD11BDAu;
#define TFR(r) { x0 += x1; x1 = (x1 << (r)) | (x1 >> (32 - (r))); x1 ^= x0; }
  x0 += k0; x1 += k1;
  TFR(13) TFR(15) TFR(26) TFR(6)
  x0 += k1; x1 += ks2 + 1u;
  TFR(17) TFR(29) TFR(16) TFR(24)
  x0 += ks2; x1 += k0 + 2u;
  TFR(13) TFR(15) TFR(26) TFR(6)
  x0 += k0; x1 += k1 + 3u;
  TFR(17) TFR(29) TFR(16) TFR(24)
  x0 += k1; x1 += ks2 + 4u;
  TFR(13) TFR(15) TFR(26) TFR(6)
  x0 += ks2; x1 += k0 + 5u;
#undef TFR
  o0 = x0; o1 = x1;
}

// JAX threefry_partitionable: out[n] = o0^o1 of tf(key, (0, n))  [verified r1]
__device__ __forceinline__ unsigned rbits(unsigned kx, unsigned ky, unsigned n) {
  unsigned a, b; tf2x32(kx, ky, 0u, n, a, b); return a ^ b;
}

// XLA-exact uniform->normal with factored fast-log (validated r2-r6, absmax 4.0)
__device__ __forceinline__ float nrm_from_bits(unsigned bits) {
  const float lo = -0.99999994039535522461f;
  float f = __uint_as_float((bits >> 9) | 0x3F800000u) - 1.0f;
  float u = fmaxf(lo, f * 2.0f + lo);
  float w = -__logf((1.0f - u) * (1.0f + u));
  float p;
  if (w < 5.0f) {
    w -= 2.5f;
    p =            2.81022636e-08f;
    p = fmaf(p, w, 3.43273939e-07f);
    p = fmaf(p, w, -3.5233877e-06f);
    p = fmaf(p, w, -4.39150654e-06f);
    p = fmaf(p, w, 0.00021858087f);
    p = fmaf(p, w, -0.00125372503f);
    p = fmaf(p, w, -0.00417768164f);
    p = fmaf(p, w, 0.246640727f);
    p = fmaf(p, w, 1.50140941f);
  } else {
    w = sqrtf(w) - 3.0f;
    p =            -0.000200214257f;
    p = fmaf(p, w, 0.000100950558f);
    p = fmaf(p, w, 0.00134934322f);
    p = fmaf(p, w, -0.00367342844f);
    p = fmaf(p, w, 0.00573950773f);
    p = fmaf(p, w, -0.0076224613f);
    p = fmaf(p, w, 0.00943887047f);
    p = fmaf(p, w, 1.00167406f);
    p = fmaf(p, w, 2.83297682f);
  }
  return 1.41421356f * (p * u);
}

// publish: relaxed agent-scope atomic store (visible at MALL by the vmcnt(0)
// drain inside the pre-barrier __syncthreads; proven r3-r6)
__device__ __forceinline__ void pubf(float* p, float v) {
  __hip_atomic_store(p, v, __ATOMIC_RELAXED, __HIP_MEMORY_SCOPE_AGENT);
}
__device__ __forceinline__ float rdf(const float* p) {
  return __hip_atomic_load(p, __ATOMIC_RELAXED, __HIP_MEMORY_SCOPE_AGENT);
}
__device__ __forceinline__ v2f rd2(const float* p) {
  unsigned long long raw = __hip_atomic_load((const unsigned long long*)p,
                                             __ATOMIC_RELAXED, __HIP_MEMORY_SCOPE_AGENT);
  v2f r; __builtin_memcpy(&r, &raw, 8); return r;
}

__global__ __launch_bounds__(WGS) __attribute__((amdgpu_waves_per_eu(8, 8)))
void rnn_fused(
    const float* __restrict__ x, const float* __restrict__ h0_in,
    const float* __restrict__ w_in, const float* __restrict__ w_hh,
    const float* __restrict__ b_hh, const float* __restrict__ w_out,
    const float* __restrict__ alpha, const float* __restrict__ beta,
    float* __restrict__ out, float* __restrict__ wsf, unsigned* __restrict__ cnts) {
  // LDS = 37888 B -> 4 WGs/CU (151552 <= 163840), same co-residency as r6 but
  // 512-thread WGs -> 8 waves/SIMD = 100% occupancy (r6 was latency-bound at 4).
  // waves_per_eu(8,8) forces the allocator to <=64 VGPR -> co-residency safe.
  __shared__ __align__(16) unsigned char smem[37888];
  float* d_lds   = (float*)smem;                // [16 e][512 tid]  32 KB
  float* a_lds   = (float*)(smem + 32768);      // [512]
  unsigned* keyl = (unsigned*)(smem + 34816);   // [64][4]
  float* olred   = (float*)(smem + 35840);      // [512]

  const int tid = threadIdx.x;
  const int b   = blockIdx.x >> 5;
  const int blk = blockIdx.x & 31;
  const int jl  = tid >> 5;            // 0..15 owned column (local)
  const int ib  = tid & 31;            // 0..31 i sub-block
  const int jg  = blk * JPW + jl;      // owned global column
  const bool leader = (ib == 0);

  float* hl  = out + HL_OFF;
  float* ol  = out + OL_OFF;
  float* hid = out + HID_OFF;
  float* nj  = out + NJ_OFF + (size_t)b * (N_HID * N_HID);
  unsigned* cnt = cnts + (size_t)b * 32;
  float* hex  = wsf + HEX_OFF;            // [2][B][512] published h
  float* aexb = wsf + AEX_OFF;            // [2][B][512] published a=tanh(h)
  float* xwg  = wsf + XWG_OFF + (size_t)blockIdx.x * (T_STEPS * JPW);

  // ---- prologue ----
  if (tid < T_STEPS) {
    unsigned f0, f1, a0, a1, b0, b1;
    tf2x32(0u, 1234u, 0u, (unsigned)tid, f0, f1);
    tf2x32(f0, f1, 0u, 0u, a0, a1);   // k1 (neuron noise)
    tf2x32(f0, f1, 0u, 1u, b0, b1);   // k2 (synaptic noise)
    keyl[tid * 4 + 0] = a0; keyl[tid * 4 + 1] = a1;
    keyl[tid * 4 + 2] = b0; keyl[tid * 4 + 3] = b1;
  }
#pragma unroll
  for (int e = 0; e < EPT; ++e) d_lds[e * 512 + tid] = 0.f;  // diff starts at 0
  // xwg[t][jj] = x[b,t,:] . w_in[blk*16+jj,:]  (global scratch; leaders read it)
#pragma unroll
  for (int r = 0; r < 2; ++r) {
    int m = r * 512 + tid;
    int tt = m >> 4, jj = m & 15;
    const float* xr = x + ((size_t)b * T_STEPS + tt) * N_IN;
    const float* wr = w_in + (size_t)(blk * JPW + jj) * N_IN;
    float s = 0.f;
#pragma unroll
    for (int k = 0; k < N_IN; ++k) s = fmaf(xr[k], wr[k], s);
    xwg[m] = s;
  }
  a_lds[tid] = tanhf(h0_in[b * N_HID + tid]);

  const float* wcol = w_hh + (size_t)jg * N_HID;  // L2-resident (1 MB total)
  const float bet = beta[jg];
  const float sb  = sqrtf(bet);
  const float al  = alpha[jg];
  const float sqa = sqrtf(al);
  const float bh  = b_hh[jg];
  float h_reg = h0_in[b * N_HID + jg];  // used by leaders

  __syncthreads();

  unsigned target = 0;
  const unsigned nb = (unsigned)(b * N_HID * N_HID) + (unsigned)jg;

  for (int t = 0; t < T_STEPS; ++t) {
    const int q = (t + 1) & 1;
    const unsigned k1x = __builtin_amdgcn_readfirstlane(keyl[t * 4 + 0]);
    const unsigned k1y = __builtin_amdgcn_readfirstlane(keyl[t * 4 + 1]);
    const unsigned k2x = __builtin_amdgcn_readfirstlane(keyl[t * 4 + 2]);
    const unsigned k2y = __builtin_amdgcn_readfirstlane(keyl[t * 4 + 3]);
    const float ajg = a_lds[jg];

    // ---- fused sweep over own 16 rows: acc (old d) + noise + d update ----
    float accd = 0.f, accw = 0.f;
#pragma unroll
    for (int e = 0; e < EPT; ++e) {
      const int i = e * 32 + ib;            // lanes read 128B-contiguous a/w
      const float av = a_lds[i];
      const float wv = wcol[i];             // global, L2-hot
      const float dv = d_lds[e * 512 + tid];
      accw = fmaf(av, wv, accw);
      accd = fmaf(av, dv, accd);
      const float z = nrm_from_bits(rbits(k2x, k2y, nb + (unsigned)i * 512u));
      d_lds[e * 512 + tid] = dv + bet * ((z * 0.002f) * sb - av * ajg);
    }
#pragma unroll
    for (int m = 1; m < 32; m <<= 1) {
      accd += __shfl_xor(accd, m);
      accw += __shfl_xor(accw, m);
    }

    // ---- leaders: h update + publish (in flight before barrier) ----
    if (leader) {
      const float xw = xwg[t * JPW + jl];
      float tmp = ((xw + accw) + bh) + accd;
      float hn = (1.f - al) * h_reg + al * tmp;
      if (t >= NOISE_START_T) {
        unsigned m0 = (unsigned)(b * N_HID + jg);
        hn += (nrm_from_bits(rbits(k1x, k1y, m0)) * 0.05f) * sqa;
      }
      h_reg = hn;
      float an = tanhf(hn);
      pubf(hex  + (size_t)(q * B_SZ + b) * N_HID + jg, hn);
      pubf(aexb + (size_t)(q * B_SZ + b) * N_HID + jg, an);
      hl[((size_t)b * T_STEPS + t) * N_HID + jg] = hn;
      if (t == T_STEPS - 1) hid[b * N_HID + jg] = hn;
    }

    // ---- per-batch barrier (32 WGs): relaxed-only atomics ----
    __syncthreads();  // all waves drain vmcnt -> publishes visible at MALL
    target += WPB;
    if (tid == 0) {
      __hip_atomic_fetch_add(cnt, 1u, __ATOMIC_RELAXED, __HIP_MEMORY_SCOPE_AGENT);
      while (__hip_atomic_load(cnt, __ATOMIC_RELAXED, __HIP_MEMORY_SCOPE_AGENT) < target)
        __builtin_amdgcn_s_sleep(1);
    }
    __builtin_amdgcn_sched_barrier(0);
    __syncthreads();

    // ---- refill a from published slot ----
    a_lds[tid] = rdf(aexb + (size_t)(q * B_SZ + b) * N_HID + tid);
    __syncthreads();

    if (blk == 0) {  // out-projection (uniform branch per WG)
      const float* hq = hex + (size_t)(q * B_SZ + b) * N_HID;
      const int o = tid & 15, qq = tid >> 4;  // qq in [0,32): 16 h values each
      const float* wo = w_out + o * N_HID;
      float p = 0.f;
#pragma unroll
      for (int m2 = 0; m2 < 8; ++m2) {
        v2f hv = rd2(hq + qq * 16 + 2 * m2);
        p = fmaf(hv.x, wo[qq * 16 + 2 * m2], p);
        p = fmaf(hv.y, wo[qq * 16 + 2 * m2 + 1], p);
      }
      olred[tid] = p;
      __syncthreads();
      if (tid < N_OUT) {
        float s = 0.f;
#pragma unroll
        for (int m = 0; m < 32; ++m) s += olred[m * 16 + tid];
        ol[((size_t)b * T_STEPS + t) * N_OUT + tid] = s;
      }
    }
  }

  // ---- epilogue: new_j[i][j] = d + w_hh (transposed read, coalesced write) ----
  __syncthreads();
  {
    const int jj = tid & 15;
    const int rr = tid >> 4;  // 0..31
#pragma unroll
    for (int g = 0; g < 16; ++g) {
      const int i = g * 32 + rr;
      const float dv = d_lds[g * 512 + jj * 32 + rr];
      const size_t o = (size_t)i * N_HID + blk * JPW + jj;
      nj[o] = dv + w_hh[o];
    }
  }
}

extern "C" void kernel_launch(void* const* d_in, const int* in_sizes, int n_in,
                              void* d_out, int out_size, void* d_ws, size_t ws_size,
                              hipStream_t stream) {
  const float* x     = (const float*)d_in[0];
  const float* h0    = (const float*)d_in[1];
  const float* win   = (const float*)d_in[2];
  const float* whh   = (const float*)d_in[3];
  const float* bhh   = (const float*)d_in[4];
  const float* wout  = (const float*)d_in[5];
  const float* alpha = (const float*)d_in[6];
  const float* beta  = (const float*)d_in[7];
  (void)in_sizes; (void)n_in; (void)out_size; (void)ws_size;

  hipMemsetAsync(d_ws, 0, CNT_BYTES, stream);  // zero per-batch barrier counters
  unsigned* cnts = (unsigned*)d_ws;
  float* wsf = (float*)((char*)d_ws + CNT_BYTES);
  rnn_fused<<<NWG, WGS, 0, stream>>>(x, h0, win, whh, bhh, wout, alpha, beta,
                                     (float*)d_out, wsf, cnts);
}

// Round 9
// 1593.996 us; speedup vs baseline: 1.2071x; 1.2071x over previous
//
#include <hip/hip_runtime.h>

#define B_SZ 32
#define T_STEPS 64
#define N_IN 64
#define N_HID 512
#define N_OUT 16
#define NOISE_START_T 16

#define WGS 256
#define WPB 32            // workgroups per batch
#define JPW 16            // j columns per WG
#define NWG (B_SZ * WPB)  // 1024

// d_out float offsets (hidden_list, output_list, hidden, new_j)
#define HL_OFF  0
#define OL_OFF  (B_SZ * T_STEPS * N_HID)
#define HID_OFF (OL_OFF + B_SZ * T_STEPS * N_OUT)
#define NJ_OFF  (HID_OFF + B_SZ * N_HID)

#define CNT_BYTES 4096
// wsf float offsets: hex[3][B][512] (h, triple-buffered: shadow-read of h(t-1)
// must not alias fast-WG publishes of h(t+1) - the r8 bug), aexb[2][B][512]
#define HEX_OFF 0
#define AEX_OFF (3 * B_SZ * N_HID)

typedef float v2f __attribute__((ext_vector_type(2)));

__device__ __forceinline__ void tf2x32(unsigned k0, unsigned k1, unsigned x0, unsigned x1,
                                       unsigned& o0, unsigned& o1) {
  unsigned ks2 = k0 ^ k1 ^ 0x1BD11BDAu;
#define TFR(r) { x0 += x1; x1 = (x1 << (r)) | (x1 >> (32 - (r))); x1 ^= x0; }
  x0 += k0; x1 += k1;
  TFR(13) TFR(15) TFR(26) TFR(6)
  x0 += k1; x1 += ks2 + 1u;
  TFR(17) TFR(29) TFR(16) TFR(24)
  x0 += ks2; x1 += k0 + 2u;
  TFR(13) TFR(15) TFR(26) TFR(6)
  x0 += k0; x1 += k1 + 3u;
  TFR(17) TFR(29) TFR(16) TFR(24)
  x0 += k1; x1 += ks2 + 4u;
  TFR(13) TFR(15) TFR(26) TFR(6)
  x0 += ks2; x1 += k0 + 5u;
#undef TFR
  o0 = x0; o1 = x1;
}

// JAX threefry_partitionable: out[n] = o0^o1 of tf(key, (0, n))  [verified r1]
__device__ __forceinline__ unsigned rbits(unsigned kx, unsigned ky, unsigned n) {
  unsigned a, b; tf2x32(kx, ky, 0u, n, a, b); return a ^ b;
}

// XLA-exact uniform->normal with factored fast-log (validated r2-r7, absmax 4.0)
__device__ __forceinline__ float nrm_from_bits(unsigned bits) {
  const float lo = -0.99999994039535522461f;
  float f = __uint_as_float((bits >> 9) | 0x3F800000u) - 1.0f;
  float u = fmaxf(lo, f * 2.0f + lo);
  float w = -__logf((1.0f - u) * (1.0f + u));
  float p;
  if (w < 5.0f) {
    w -= 2.5f;
    p =            2.81022636e-08f;
    p = fmaf(p, w, 3.43273939e-07f);
    p = fmaf(p, w, -3.5233877e-06f);
    p = fmaf(p, w, -4.39150654e-06f);
    p = fmaf(p, w, 0.00021858087f);
    p = fmaf(p, w, -0.00125372503f);
    p = fmaf(p, w, -0.00417768164f);
    p = fmaf(p, w, 0.246640727f);
    p = fmaf(p, w, 1.50140941f);
  } else {
    w = sqrtf(w) - 3.0f;
    p =            -0.000200214257f;
    p = fmaf(p, w, 0.000100950558f);
    p = fmaf(p, w, 0.00134934322f);
    p = fmaf(p, w, -0.00367342844f);
    p = fmaf(p, w, 0.00573950773f);
    p = fmaf(p, w, -0.0076224613f);
    p = fmaf(p, w, 0.00943887047f);
    p = fmaf(p, w, 1.00167406f);
    p = fmaf(p, w, 2.83297682f);
  }
  return 1.41421356f * (p * u);
}

// publish: relaxed agent-scope atomic store (visible at MALL after the vmcnt(0)
// drain inside the pre-arrive __syncthreads; proven r3-r7)
__device__ __forceinline__ void pubf(float* p, float v) {
  __hip_atomic_store(p, v, __ATOMIC_RELAXED, __HIP_MEMORY_SCOPE_AGENT);
}
__device__ __forceinline__ v2f rd2(const float* p) {
  unsigned long long raw = __hip_atomic_load((const unsigned long long*)p,
                                             __ATOMIC_RELAXED, __HIP_MEMORY_SCOPE_AGENT);
  v2f r; __builtin_memcpy(&r, &raw, 8); return r;
}

__global__ __launch_bounds__(WGS) __attribute__((amdgpu_waves_per_eu(4, 4)))
void rnn_fused(
    const float* __restrict__ x, const float* __restrict__ h0_in,
    const float* __restrict__ w_in, const float* __restrict__ w_hh,
    const float* __restrict__ b_hh, const float* __restrict__ w_out,
    const float* __restrict__ alpha, const float* __restrict__ beta,
    float* __restrict__ out, float* __restrict__ wsf, unsigned* __restrict__ cnts) {
  // LDS = exactly 40960 B -> 4 WGs/CU: all 1024 WGs co-resident (barrier-safe).
  // r6-proven resource shape: 256 thr, VGPR 64, d state in LDS (no spill).
  __shared__ __align__(16) unsigned char smem[40960];
  float* d_lds   = (float*)smem;                // [32 e][256 tid]
  float* a_lds   = (float*)(smem + 32768);      // [512]
  float* xw_lds  = (float*)(smem + 34816);      // [64][16]
  unsigned* keyl = (unsigned*)(smem + 38912);   // [64][4]
  float* olred   = (float*)(smem + 39936);      // [256]

  const int tid = threadIdx.x;
  const int b   = blockIdx.x >> 5;
  const int blk = blockIdx.x & 31;
  const int jl  = tid >> 4;            // owned column (local)
  const int ib  = tid & 15;            // i sub-block
  const int jg  = blk * JPW + jl;      // owned global column
  const bool leader = (ib == 0);

  float* hl  = out + HL_OFF;
  float* ol  = out + OL_OFF;
  float* hid = out + HID_OFF;
  float* nj  = out + NJ_OFF + (size_t)b * (N_HID * N_HID);
  unsigned* cnt = cnts + (size_t)b * 32;
  float* hex  = wsf + HEX_OFF;            // [3][B][512] published h (slot = t%3)
  float* aexb = wsf + AEX_OFF;            // [2][B][512] published a (parity)

  // ---- prologue (identical to r6) ----
  if (tid < T_STEPS) {
    unsigned f0, f1, a0, a1, b0, b1;
    tf2x32(0u, 1234u, 0u, (unsigned)tid, f0, f1);
    tf2x32(f0, f1, 0u, 0u, a0, a1);   // k1 (neuron noise)
    tf2x32(f0, f1, 0u, 1u, b0, b1);   // k2 (synaptic noise)
    keyl[tid * 4 + 0] = a0; keyl[tid * 4 + 1] = a1;
    keyl[tid * 4 + 2] = b0; keyl[tid * 4 + 3] = b1;
  }
#pragma unroll
  for (int k = 0; k < 32; ++k) d_lds[k * 256 + tid] = 0.f;
#pragma unroll
  for (int r = 0; r < 4; ++r) {
    int m = r * 256 + tid;
    int tt = m >> 4, jj = m & 15;
    const float* xr = x + ((size_t)b * T_STEPS + tt) * N_IN;
    const float* wr = w_in + (size_t)(blk * JPW + jj) * N_IN;
    float s = 0.f;
#pragma unroll
    for (int k = 0; k < N_IN; ++k) s = fmaf(xr[k], wr[k], s);
    xw_lds[tt * JPW + jj] = s;
  }
  a_lds[tid]       = tanhf(h0_in[b * N_HID + tid]);
  a_lds[tid + 256] = tanhf(h0_in[b * N_HID + tid + 256]);

  const float* whrow = w_hh + (size_t)jg * N_HID;  // L2-resident (1 MB total)
  const float bet = beta[jg];
  const float sb  = sqrtf(bet);
  const float al  = alpha[jg];
  const float sqa = sqrtf(al);
  const float bh  = b_hh[jg];
  float h_reg = h0_in[b * N_HID + jg];

  __syncthreads();

  unsigned target = 0;
  const unsigned nb = (unsigned)(b * N_HID * N_HID) + (unsigned)jg;
  int hs = 0;  // t % 3 (publish slot for h)

  for (int t = 0; t < T_STEPS; ++t) {
    const int q = (t + 1) & 1;
    const unsigned k1x = __builtin_amdgcn_readfirstlane(keyl[t * 4 + 0]);
    const unsigned k1y = __builtin_amdgcn_readfirstlane(keyl[t * 4 + 1]);
    const unsigned k2x = __builtin_amdgcn_readfirstlane(keyl[t * 4 + 2]);
    const unsigned k2y = __builtin_amdgcn_readfirstlane(keyl[t * 4 + 3]);
    const float ajg = a_lds[jg];

    // ---- CRITICAL PATH: acc-sweep only (no noise) ----
    float accd = 0.f, accw = 0.f;
#pragma unroll
    for (int k = 0; k < 8; ++k) {
      const int i = k * 64 + ib * 4;
      float4 av = *(const float4*)&a_lds[i];
      float4 wv = *(const float4*)&whrow[i];       // global, L2-hot
      float d0 = d_lds[(k * 4 + 0) * 256 + tid];
      float d1 = d_lds[(k * 4 + 1) * 256 + tid];
      float d2 = d_lds[(k * 4 + 2) * 256 + tid];
      float d3 = d_lds[(k * 4 + 3) * 256 + tid];
      accw = fmaf(av.x, wv.x, accw); accw = fmaf(av.y, wv.y, accw);
      accw = fmaf(av.z, wv.z, accw); accw = fmaf(av.w, wv.w, accw);
      accd = fmaf(av.x, d0, accd); accd = fmaf(av.y, d1, accd);
      accd = fmaf(av.z, d2, accd); accd = fmaf(av.w, d3, accd);
    }
#pragma unroll
    for (int m = 1; m < 16; m <<= 1) {
      accd += __shfl_xor(accd, m);
      accw += __shfl_xor(accw, m);
    }

    // ---- leaders: h update + publish ----
    if (leader) {
      const float xw = xw_lds[t * JPW + jl];
      float tmp = ((xw + accw) + bh) + accd;
      float hn = (1.f - al) * h_reg + al * tmp;
      if (t >= NOISE_START_T) {
        unsigned m0 = (unsigned)(b * N_HID + jg);
        hn += (nrm_from_bits(rbits(k1x, k1y, m0)) * 0.05f) * sqa;
      }
      h_reg = hn;
      float an = tanhf(hn);
      pubf(hex  + (size_t)(hs * B_SZ + b) * N_HID + jg, hn);
      pubf(aexb + (size_t)(q  * B_SZ + b) * N_HID + jg, an);
      hl[((size_t)b * T_STEPS + t) * N_HID + jg] = hn;
      if (t == T_STEPS - 1) hid[b * N_HID + jg] = hn;
    }

    // ---- ARRIVE EARLY: publishes drained by this syncthreads, then signal ----
    __syncthreads();                 // vmcnt(0) drain -> publishes at MALL
    target += WPB;
    if (tid == 0)
      __hip_atomic_fetch_add(cnt, 1u, __ATOMIC_RELAXED, __HIP_MEMORY_SCOPE_AGENT);

    // ---- BARRIER SHADOW: threefry noise + d update (90% of VALU work).
    //      Bit-identical per-element arithmetic to r6. ----
#pragma unroll
    for (int k = 0; k < 8; ++k) {
      const int i = k * 64 + ib * 4;
      float4 av = *(const float4*)&a_lds[i];
      const unsigned n = nb + (unsigned)i * 512u;
      float z0 = nrm_from_bits(rbits(k2x, k2y, n));
      float z1 = nrm_from_bits(rbits(k2x, k2y, n + 512u));
      float z2 = nrm_from_bits(rbits(k2x, k2y, n + 1024u));
      float z3 = nrm_from_bits(rbits(k2x, k2y, n + 1536u));
      d_lds[(k * 4 + 0) * 256 + tid] += bet * ((z0 * 0.002f) * sb - av.x * ajg);
      d_lds[(k * 4 + 1) * 256 + tid] += bet * ((z1 * 0.002f) * sb - av.y * ajg);
      d_lds[(k * 4 + 2) * 256 + tid] += bet * ((z2 * 0.002f) * sb - av.z * ajg);
      d_lds[(k * 4 + 3) * 256 + tid] += bet * ((z3 * 0.002f) * sb - av.w * ajg);
    }

    // ---- SHADOW (blk0): out-projection of step t-1 from slot (t-1)%3.
    //      Writers in-flight target t%3 (own) or (t+1)%3 (fast WGs) - both
    //      distinct mod 3 -> no aliasing (the r8 parity-2 race is closed). ----
    if (blk == 0 && t > 0) {
      const int ps = (hs == 0) ? 2 : hs - 1;   // (t-1) % 3
      const float* hq = hex + (size_t)(ps * B_SZ + b) * N_HID;
      const int o = tid & 15, qq = tid >> 4;
      const float* wo = w_out + o * N_HID;
      float p = 0.f;
#pragma unroll
      for (int m2 = 0; m2 < 16; ++m2) {
        v2f hv = rd2(hq + qq * 32 + 2 * m2);
        p = fmaf(hv.x, wo[qq * 32 + 2 * m2], p);
        p = fmaf(hv.y, wo[qq * 32 + 2 * m2 + 1], p);
      }
      olred[tid] = p;
      __syncthreads();
      if (tid < N_OUT) {
        float s = 0.f;
#pragma unroll
        for (int m = 0; m < 16; ++m) s += olred[m * 16 + tid];
        ol[((size_t)b * T_STEPS + (t - 1)) * N_OUT + tid] = s;
      }
    }

    // ---- WAIT + refill ----
    if (tid == 0) {
      while (__hip_atomic_load(cnt, __ATOMIC_RELAXED, __HIP_MEMORY_SCOPE_AGENT) < target)
        __builtin_amdgcn_s_sleep(1);
    }
    __builtin_amdgcn_sched_barrier(0);
    __syncthreads();
    {
      const float* aq = aexb + (size_t)(q * B_SZ + b) * N_HID;
      v2f av = rd2(aq + 2 * tid);
      a_lds[2 * tid] = av.x; a_lds[2 * tid + 1] = av.y;
    }
    __syncthreads();

    hs = (hs == 2) ? 0 : hs + 1;
  }

  // ---- final out-projection: step T-1 lives in slot (T-1)%3; no writers ----
  if (blk == 0) {
    const float* hq = hex + (size_t)(((T_STEPS - 1) % 3) * B_SZ + b) * N_HID;
    const int o = tid & 15, qq = tid >> 4;
    const float* wo = w_out + o * N_HID;
    float p = 0.f;
#pragma unroll
    for (int m2 = 0; m2 < 16; ++m2) {
      v2f hv = rd2(hq + qq * 32 + 2 * m2);
      p = fmaf(hv.x, wo[qq * 32 + 2 * m2], p);
      p = fmaf(hv.y, wo[qq * 32 + 2 * m2 + 1], p);
    }
    olred[tid] = p;
    __syncthreads();
    if (tid < N_OUT) {
      float s = 0.f;
#pragma unroll
      for (int m = 0; m < 16; ++m) s += olred[m * 16 + tid];
      ol[((size_t)b * T_STEPS + (T_STEPS - 1)) * N_OUT + tid] = s;
    }
  }

  // ---- epilogue: new_j[i][j] = d + w_hh (r6-identical) ----
  __syncthreads();
  {
    const int jj = tid & 15;
#pragma unroll
    for (int g = 0; g < 32; ++g) {
      const int i = g * 16 + (tid >> 4);
      const int k = i >> 6, e = i & 3, ibb = (i >> 2) & 15;
      const float dv = d_lds[(k * 4 + e) * 256 + jj * 16 + ibb];
      const size_t o = (size_t)i * N_HID + blk * JPW + jj;
      nj[o] = dv + w_hh[o];
    }
  }
}

extern "C" void kernel_launch(void* const* d_in, const int* in_sizes, int n_in,
                              void* d_out, int out_size, void* d_ws, size_t ws_size,
                              hipStream_t stream) {
  const float* x     = (const float*)d_in[0];
  const float* h0    = (const float*)d_in[1];
  const float* win   = (const float*)d_in[2];
  const float* whh   = (const float*)d_in[3];
  const float* bhh   = (const float*)d_in[4];
  const float* wout  = (const float*)d_in[5];
  const float* alpha = (const float*)d_in[6];
  const float* beta  = (const float*)d_in[7];
  (void)in_sizes; (void)n_in; (void)out_size; (void)ws_size;

  hipMemsetAsync(d_ws, 0, CNT_BYTES, stream);  // zero per-batch barrier counters
  unsigned* cnts = (unsigned*)d_ws;
  float* wsf = (float*)((char*)d_ws + CNT_BYTES);  // hex[3][B][512] + aexb[2][B][512]
  rnn_fused<<<NWG, WGS, 0, stream>>>(x, h0, win, whh, bhh, wout, alpha, beta,
                                     (float*)d_out, wsf, cnts);
}